// Round 7
// baseline (167.706 us; speedup 1.0000x reference)
//
#include <hip/hip_runtime.h>
#include <hip/hip_bf16.h>

// Node_GAT N=16, M=1024, D=64, H=4.
// R11: LDS-free attn main loop. proj writes Q and V^T in FRAG-MAJOR layout
// (Q: [(jb32*4+ks)*2+hf][m31][8], V^T: [((jt*4+ks)*2+eh)*2+hf][m31][8]) so attn
// loads every MFMA fragment directly from global, 16B/lane fully coalesced.
// attn j-loop: 16 coalesced loads + 16 MFMA + softmax — ZERO LDS ops, ZERO barriers
// (waves fully decoupled; #pragma unroll 2 for cross-iteration pipelining).
// Softmax denom broadcast via __shfl (wave-local); single barrier at epilogue for
// coalesced DX store. Deferred-PV and setprio removed (both null: R8/R10).
// Rest unchanged: wave-local P (S^T = mfma(Q,K)), exp2 in-reg, cvt_pk+permlane32_swap,
// 128 i-rows/block, K pre-scaled by log2e, XCD-bijective block swizzle.

#define NB 16
#define MM 1024
#define DD 64
#define HH 4
#define NEG 0.2f
#define AST 72   // LDS row stride (shorts): 16B-aligned rows
#define DST 264  // dec LDS stride (256-wide rows)
#define LOG2E 1.44269504088896f

typedef __attribute__((ext_vector_type(8))) short bf16x8;
typedef __attribute__((ext_vector_type(8))) _Float16 f16x8;
typedef __attribute__((ext_vector_type(16))) float f32x16;
typedef __attribute__((ext_vector_type(4))) unsigned int uint4v;
typedef __attribute__((ext_vector_type(2))) unsigned int uint2v;

__device__ inline unsigned short f2bf(float f) {
  unsigned int u = __builtin_bit_cast(unsigned int, f);
  unsigned int r = (u + 0x7FFFu + ((u >> 16) & 1u)) >> 16;
  return (unsigned short)r;
}
__device__ inline unsigned short f2h(float f) {
  _Float16 h = (_Float16)f;
  return __builtin_bit_cast(unsigned short, h);
}
__device__ inline unsigned int pk_bf16(float lo, float hi) {
  unsigned int r;
  asm("v_cvt_pk_bf16_f32 %0, %1, %2" : "=v"(r) : "v"(lo), "v"(hi));
  return r;
}
// swap32(a,b): a' = {hf0: own.a, hf1: partner.b}; b' = {hf0: partner.a, hf1: own.b}
__device__ inline void swap32(unsigned int& a, unsigned int& b) {
  uint2v r = __builtin_amdgcn_permlane32_swap(a, b, false, false);
  a = r.x;
  b = r.y;
}

// ---------------- Kernel 0: weight prep -> f16 ----------------
__global__ __launch_bounds__(256) void prep_kernel(
    const float* __restrict__ Wk, const float* __restrict__ Wq,
    const float* __restrict__ Wv, const float* __restrict__ Wdec,
    unsigned short* __restrict__ Wf) {
  const int idx = (blockIdx.x * 256 + threadIdx.x) * 4;
  const int seg = idx >> 14, local = idx & 16383;
  const float* src = seg == 0 ? Wk : seg == 1 ? Wq : seg == 2 ? Wv : Wdec;
  float4 v = *(const float4*)&src[local];
  unsigned short p[4] = {f2h(v.x), f2h(v.y), f2h(v.z), f2h(v.w)};
  *(uint2*)&Wf[idx] = *(uint2*)p;
}

// ---------------- Kernel 1: projections, f16 32x32x16 MFMA ----------------
// grid (256, 12): 64 m-rows x combo(mat*4+h). K (scaled by log2e) -> linear f16;
// Q -> FRAG-MAJOR f16; V -> FRAG-MAJOR V^T bf16.
__global__ __launch_bounds__(256) void proj_kernel(
    const float* __restrict__ x, const unsigned short* __restrict__ Wf,
    const float* __restrict__ bk, const float* __restrict__ bq, const float* __restrict__ bv,
    unsigned short* __restrict__ Kf, unsigned short* __restrict__ Qf,
    unsigned short* __restrict__ Vtg) {
  __shared__ unsigned short xs[64 * AST];
  __shared__ unsigned short ob[64 * AST];
  const int t = threadIdx.x;
  const int r0 = blockIdx.x * 64;
  const int combo = blockIdx.y, mat = combo >> 2, h = combo & 3;
  const int n = r0 >> 10, ml = r0 & 1023;
  const float* bias = mat == 0 ? bk : (mat == 1 ? bq : bv);

#pragma unroll
  for (int rep = 0; rep < 2; ++rep) {
    int idx = rep * 256 + t, row = idx >> 3, c8 = (idx & 7) * 8;
    float4 a = *(const float4*)&x[(size_t)(r0 + row) * DD + c8];
    float4 b = *(const float4*)&x[(size_t)(r0 + row) * DD + c8 + 4];
    unsigned short p[8] = {f2h(a.x), f2h(a.y), f2h(a.z), f2h(a.w),
                           f2h(b.x), f2h(b.y), f2h(b.z), f2h(b.w)};
    *(uint4*)&xs[row * AST + c8] = *(uint4*)p;
  }
  __syncthreads();

  const int w = t >> 6, lane = t & 63, m31 = lane & 31, hf = lane >> 5;
  const int mi = w >> 1, ne = w & 1;
  const int ecol = h * 64 + ne * 32 + m31;
  const float bb = bias[ecol];

  f32x16 C;
#pragma unroll
  for (int r = 0; r < 16; ++r) C[r] = 0.f;
#pragma unroll
  for (int ks = 0; ks < 4; ++ks) {
    f16x8 xa = *(f16x8*)&xs[(mi * 32 + m31) * AST + ks * 16 + hf * 8];
    f16x8 wb = *(const f16x8*)&Wf[(size_t)mat * 16384 + (size_t)ecol * DD + ks * 16 + hf * 8];
    C = __builtin_amdgcn_mfma_f32_32x32x16_f16(xa, wb, C, 0, 0, 0);
  }

  if (mat < 2) {
    const float ksc = (mat == 0) ? LOG2E : 1.0f;  // fold exp's log2e into K
#pragma unroll
    for (int r = 0; r < 16; ++r) {
      int rr = (r & 3) + 8 * (r >> 2) + 4 * hf;
      ob[(mi * 32 + rr) * AST + ne * 32 + m31] = f2h((C[r] + bb) * ksc);
    }
  } else {
    // V transposed staging: ob[e][m_local], bf16
#pragma unroll
    for (int r = 0; r < 16; ++r) {
      int rr = (r & 3) + 8 * (r >> 2) + 4 * hf;
      ob[(ne * 32 + m31) * AST + mi * 32 + rr] = f2bf(C[r] + bb);
    }
  }
  __syncthreads();

  if (mat == 0) {
    // K: linear (n,h,m,e) — attn reads kfrag once per block, gather OK
    const size_t obase = (((size_t)n * HH + h) * MM + ml) * DD;
#pragma unroll
    for (int rep = 0; rep < 2; ++rep) {
      int idx = rep * 256 + t, row = idx >> 3, c8 = (idx & 7) * 8;
      *(uint4*)&Kf[obase + (size_t)row * DD + c8] = *(uint4*)&ob[row * AST + c8];
    }
  } else if (mat == 1) {
    // Q frag-major: dst short-offset = base + ml*64 + idx*8, where
    // idx = jb32l*256 + ks*64 + hf2*32 + mr  <->  frag (jb32=ml/32+jb32l, ks, hf2, mr)
    const size_t obase = (((size_t)n * HH + h) * MM + ml) * DD;
#pragma unroll
    for (int rep = 0; rep < 2; ++rep) {
      int idx = rep * 256 + t;
      int jb32l = idx >> 8, ks = (idx >> 6) & 3, hf2 = (idx >> 5) & 1, mr = idx & 31;
      *(uint4*)&Qf[obase + (size_t)idx * 8] =
          *(uint4*)&ob[(jb32l * 32 + mr) * AST + ks * 16 + hf2 * 8];
    }
  } else {
    // V^T frag-major: dst short-offset = baseT + (ml/64)*4096 + idx*8, where
    // idx = ks*128 + eh*64 + hf2*32 + mr  <->  frag (jt=ml/64, ks, eh, hf2, mr)
    const size_t obaseT = (((size_t)n * HH + h) * DD) * MM + (size_t)(ml >> 6) * 4096;
#pragma unroll
    for (int rep = 0; rep < 2; ++rep) {
      int idx = rep * 256 + t;
      int ks = idx >> 7, eh = (idx >> 6) & 1, hf2 = (idx >> 5) & 1, mr = idx & 31;
      *(uint4*)&Vtg[obaseT + (size_t)idx * 8] =
          *(uint4*)&ob[(eh * 32 + mr) * AST + ks * 16 + hf2 * 8];
    }
  }
}

// ---------------- Kernel 2: flash attention, LDS-free main loop ----------------
// grid (8, H, N), 256 thr = 4 waves. Block: 128 i x 1024 j; wave w owns i-strip w*32..+32.
// Per j-tile: 16 coalesced frag loads (global, L2-hot) + S^T mfma(Q,K) + in-reg softmax
// + PV. No LDS, no barriers in loop. Epilogue: shfl denom + LDS-staged coalesced store.
__global__ __launch_bounds__(256, 2) void attn_kernel(
    const unsigned short* __restrict__ Kf, const unsigned short* __restrict__ Qf,
    const unsigned short* __restrict__ Vtg, const float* __restrict__ x,
    unsigned short* __restrict__ DX) {
  __shared__ __align__(16) unsigned short sm[128 * AST];  // epilogue dx staging only

  const int t = threadIdx.x;
  const int w = t >> 6, lane = t & 63;
  const int m31 = lane & 31, hf = lane >> 5;

  // XCD-bijective swizzle: xcd = slot&7 gets 8 whole (n,h) groups.
  const int slot = blockIdx.x + 8 * (blockIdx.y + HH * (int)blockIdx.z);  // 0..511
  const int xcd = slot & 7, within = slot >> 3;
  const int grp = xcd * 8 + (within >> 3);  // 0..63 = n*4+h
  const int ib = within & 7;
  const int n = grp >> 2, h = grp & 3;
  const int i0 = ib * 128;

  const size_t base = (((size_t)n * HH + h) * MM) * DD;
  const size_t baseT = (((size_t)n * HH + h) * DD) * MM;
  const unsigned short* Qp = Qf + base;
  const unsigned short* Vp = Vtg + baseT;

  // K fragments: B-operand cols i = i0 + w*32 + m31 (log2e pre-folded in proj)
  f16x8 kfrag[4];
#pragma unroll
  for (int ks = 0; ks < 4; ++ks)
    kfrag[ks] = *(const f16x8*)&Kf[base + (size_t)(i0 + w * 32 + m31) * DD + ks * 16 + hf * 8];

  f32x16 agg0, agg1;
#pragma unroll
  for (int r = 0; r < 16; ++r) { agg0[r] = 0.f; agg1[r] = 0.f; }
  float lac = 0.f;

  const int loff = hf * 256 + m31 * 8;  // lane term, shared by all frag loads

#pragma unroll 2
  for (int jt = 0; jt < 16; ++jt) {
    const unsigned short* Qj = Qp + (size_t)jt * 4096;
    const unsigned short* Vj = Vp + (size_t)jt * 4096;

    // 16 coalesced fragment loads (16B/lane, 1KB/instr)
    f16x8 qa0[4], qa1[4];
    bf16x8 bv0[4], bv1[4];
#pragma unroll
    for (int ks = 0; ks < 4; ++ks) {
      qa0[ks] = *(const f16x8*)&Qj[ks * 512 + loff];
      qa1[ks] = *(const f16x8*)&Qj[2048 + ks * 512 + loff];
      bv0[ks] = *(const bf16x8*)&Vj[ks * 1024 + loff];
      bv1[ks] = *(const bf16x8*)&Vj[ks * 1024 + 512 + loff];
    }

    bf16x8 pa[4];
    // ---- S tile0: D[j][i] = mfma(Q rows j, K cols i); lane (m31,hf): i=m31 ----
    f32x16 C;
#pragma unroll
    for (int r = 0; r < 16; ++r) C[r] = 0.f;
#pragma unroll
    for (int ks = 0; ks < 4; ++ks)
      C = __builtin_amdgcn_mfma_f32_32x32x16_f16(qa0[ks], kfrag[ks], C, 0, 0, 0);
#pragma unroll
    for (int r = 0; r < 16; ++r) {
      float s = C[r];
      s = fmaxf(s, NEG * s);  // leaky (log2e scale commutes with max)
      s = __builtin_amdgcn_exp2f(s);
      lac += s;
      C[r] = s;
    }
    {
      unsigned int p01 = pk_bf16(C[0], C[1]), p23 = pk_bf16(C[2], C[3]);
      unsigned int p45 = pk_bf16(C[4], C[5]), p67 = pk_bf16(C[6], C[7]);
      swap32(p01, p45);
      swap32(p23, p67);
      uint4v wlo = {p01, p23, p45, p67};
      pa[0] = __builtin_bit_cast(bf16x8, wlo);
      unsigned int p89 = pk_bf16(C[8], C[9]), pAB = pk_bf16(C[10], C[11]);
      unsigned int pCD = pk_bf16(C[12], C[13]), pEF = pk_bf16(C[14], C[15]);
      swap32(p89, pCD);
      swap32(pAB, pEF);
      uint4v whi = {p89, pAB, pCD, pEF};
      pa[1] = __builtin_bit_cast(bf16x8, whi);
    }
    // ---- S tile1 ----
#pragma unroll
    for (int r = 0; r < 16; ++r) C[r] = 0.f;
#pragma unroll
    for (int ks = 0; ks < 4; ++ks)
      C = __builtin_amdgcn_mfma_f32_32x32x16_f16(qa1[ks], kfrag[ks], C, 0, 0, 0);
#pragma unroll
    for (int r = 0; r < 16; ++r) {
      float s = C[r];
      s = fmaxf(s, NEG * s);
      s = __builtin_amdgcn_exp2f(s);
      lac += s;
      C[r] = s;
    }
    {
      unsigned int p01 = pk_bf16(C[0], C[1]), p23 = pk_bf16(C[2], C[3]);
      unsigned int p45 = pk_bf16(C[4], C[5]), p67 = pk_bf16(C[6], C[7]);
      swap32(p01, p45);
      swap32(p23, p67);
      uint4v wlo = {p01, p23, p45, p67};
      pa[2] = __builtin_bit_cast(bf16x8, wlo);
      unsigned int p89 = pk_bf16(C[8], C[9]), pAB = pk_bf16(C[10], C[11]);
      unsigned int pCD = pk_bf16(C[12], C[13]), pEF = pk_bf16(C[14], C[15]);
      swap32(p89, pCD);
      swap32(pAB, pEF);
      uint4v whi = {p89, pAB, pCD, pEF};
      pa[3] = __builtin_bit_cast(bf16x8, whi);
    }

    // ---- PV: agg[i][e] += P[i][j] * V[j][e] ----
#pragma unroll
    for (int ks = 0; ks < 4; ++ks) {
      agg0 = __builtin_amdgcn_mfma_f32_32x32x16_bf16(pa[ks], bv0[ks], agg0, 0, 0, 0);
      agg1 = __builtin_amdgcn_mfma_f32_32x32x16_bf16(pa[ks], bv1[ks], agg1, 0, 0, 0);
    }
  }

  // denom: lsum(lane) = l[row m31] (both halves); broadcast to row rr via shfl.
  const float lsum = lac + __shfl_xor(lac, 32);

  // epilogue: dx = leaky(agg/l) - x -> f16 stage in sm -> coalesced store (concat layout)
#pragma unroll
  for (int r = 0; r < 16; ++r) {
    const int rr = (r & 3) + 8 * (r >> 2) + 4 * hf;
    const float rl = 1.0f / __shfl(lsum, rr);
    const size_t xrow = ((size_t)n * MM + i0 + w * 32 + rr) * DD;
    float v0 = agg0[r] * rl;
    v0 = fmaxf(v0, NEG * v0);
    v0 -= x[xrow + m31];
    sm[(w * 32 + rr) * AST + m31] = f2h(v0);
    float v1 = agg1[r] * rl;
    v1 = fmaxf(v1, NEG * v1);
    v1 -= x[xrow + 32 + m31];
    sm[(w * 32 + rr) * AST + 32 + m31] = f2h(v1);
  }
  __syncthreads();
#pragma unroll
  for (int rep = 0; rep < 4; ++rep) {
    const int idx = rep * 256 + t, row = idx >> 3, cc = (idx & 7) * 8;
    *(uint4*)&DX[((size_t)n * MM + i0 + row) * (HH * DD) + h * DD + cc] =
        *(uint4*)&sm[row * AST + cc];
  }
}

// ---------------- Kernel 3: decoder, f16 32x32x16 MFMA ----------------
__global__ __launch_bounds__(256) void dec_kernel(
    const unsigned short* __restrict__ DX, const unsigned short* __restrict__ Wdf,
    const float* __restrict__ bdec, float* __restrict__ out) {
  __shared__ unsigned short dxs[64 * DST];
  const int t = threadIdx.x;
  const int w = t >> 6, lane = t & 63, m31 = lane & 31, hf = lane >> 5;
  const int mi = w >> 1, nd = w & 1;
  const int r0 = blockIdx.x * 64;
#pragma unroll
  for (int rep = 0; rep < 8; ++rep) {
    int idx = rep * 256 + t, row = idx >> 5, c8 = (idx & 31) * 8;
    *(uint4*)&dxs[row * DST + c8] = *(const uint4*)&DX[(size_t)(r0 + row) * 256 + c8];
  }
  __syncthreads();
  const float bb = bdec[nd * 32 + m31];
  f32x16 C;
#pragma unroll
  for (int r = 0; r < 16; ++r) C[r] = 0.f;
#pragma unroll
  for (int ks = 0; ks < 16; ++ks) {
    f16x8 aD = *(f16x8*)&dxs[(mi * 32 + m31) * DST + ks * 16 + hf * 8];
    f16x8 bW = *(const f16x8*)&Wdf[(size_t)(nd * 32 + m31) * 256 + ks * 16 + hf * 8];
    C = __builtin_amdgcn_mfma_f32_32x32x16_f16(aD, bW, C, 0, 0, 0);
  }
#pragma unroll
  for (int r = 0; r < 16; ++r) {
    int rr = (r & 3) + 8 * (r >> 2) + 4 * hf;
    out[(size_t)(r0 + mi * 32 + rr) * DD + nd * 32 + m31] = C[r] + bb;
  }
}

extern "C" void kernel_launch(void* const* d_in, const int* in_sizes, int n_in,
                              void* d_out, int out_size, void* d_ws, size_t ws_size,
                              hipStream_t stream) {
  const float* x    = (const float*)d_in[0];
  const float* Wk   = (const float*)d_in[2];
  const float* bk   = (const float*)d_in[3];
  const float* Wq   = (const float*)d_in[4];
  const float* bq   = (const float*)d_in[5];
  const float* Wv   = (const float*)d_in[6];
  const float* bv   = (const float*)d_in[7];
  const float* Wdec = (const float*)d_in[8];
  const float* bdec = (const float*)d_in[9];
  float* out = (float*)d_out;

  const size_t seg = (size_t)NB * HH * MM * DD;
  unsigned short* Kf  = (unsigned short*)d_ws;
  unsigned short* Qf  = Kf + seg;
  unsigned short* Vt  = Qf + seg;
  unsigned short* DXp = Vt + seg;
  unsigned short* Wf  = DXp + seg;
  unsigned short* Wdf = Wf + 3 * 16384;

  prep_kernel<<<64, 256, 0, stream>>>(Wk, Wq, Wv, Wdec, Wf);
  proj_kernel<<<dim3(256, 12), 256, 0, stream>>>(x, Wf, bk, bq, bv, Kf, Qf, Vt);
  attn_kernel<<<dim3(8, HH, NB), 256, 0, stream>>>(Kf, Qf, Vt, x, DXp);
  dec_kernel<<<NB * MM / 64, 256, 0, stream>>>(DXp, Wdf, bdec, out);
}

// Round 8
// 151.063 us; speedup vs baseline: 1.1102x; 1.1102x over previous
//
#include <hip/hip_runtime.h>
#include <hip/hip_bf16.h>

// Node_GAT N=16, M=1024, D=64, H=4.
// R12 = R11 (LDS-free attn, frag-major Q/V^T) + REGISTER DOUBLE-BUFFER pipeline:
// R11 regressed (attn 49us, MfmaUtil 12.6, VALUBusy 28 — exposed-latency signature)
// because removing LDS also removed the prefetch distance. R12 rebuilds it in regs:
// manually 2x-unrolled j-loop with named buffer sets A/B (literal indices only);
// issue loads(B,jt+1) -> compute(A,jt) -> issue loads(A,jt+2) -> compute(B,jt+1).
// Still zero LDS ops / zero barriers in the loop; waves fully decoupled.
// Rest unchanged: wave-local P (S^T = mfma(Q,K)), exp2 in-reg, cvt_pk+permlane32_swap,
// 128 i-rows/block, K pre-scaled by log2e, XCD-bijective block swizzle.

#define NB 16
#define MM 1024
#define DD 64
#define HH 4
#define NEG 0.2f
#define AST 72   // LDS row stride (shorts): 16B-aligned rows
#define DST 264  // dec LDS stride (256-wide rows)
#define LOG2E 1.44269504088896f

typedef __attribute__((ext_vector_type(8))) short bf16x8;
typedef __attribute__((ext_vector_type(8))) _Float16 f16x8;
typedef __attribute__((ext_vector_type(16))) float f32x16;
typedef __attribute__((ext_vector_type(4))) unsigned int uint4v;
typedef __attribute__((ext_vector_type(2))) unsigned int uint2v;

__device__ inline unsigned short f2bf(float f) {
  unsigned int u = __builtin_bit_cast(unsigned int, f);
  unsigned int r = (u + 0x7FFFu + ((u >> 16) & 1u)) >> 16;
  return (unsigned short)r;
}
__device__ inline unsigned short f2h(float f) {
  _Float16 h = (_Float16)f;
  return __builtin_bit_cast(unsigned short, h);
}
__device__ inline unsigned int pk_bf16(float lo, float hi) {
  unsigned int r;
  asm("v_cvt_pk_bf16_f32 %0, %1, %2" : "=v"(r) : "v"(lo), "v"(hi));
  return r;
}
// swap32(a,b): a' = {hf0: own.a, hf1: partner.b}; b' = {hf0: partner.a, hf1: own.b}
__device__ inline void swap32(unsigned int& a, unsigned int& b) {
  uint2v r = __builtin_amdgcn_permlane32_swap(a, b, false, false);
  a = r.x;
  b = r.y;
}

// ---------------- Kernel 0: weight prep -> f16 ----------------
__global__ __launch_bounds__(256) void prep_kernel(
    const float* __restrict__ Wk, const float* __restrict__ Wq,
    const float* __restrict__ Wv, const float* __restrict__ Wdec,
    unsigned short* __restrict__ Wf) {
  const int idx = (blockIdx.x * 256 + threadIdx.x) * 4;
  const int seg = idx >> 14, local = idx & 16383;
  const float* src = seg == 0 ? Wk : seg == 1 ? Wq : seg == 2 ? Wv : Wdec;
  float4 v = *(const float4*)&src[local];
  unsigned short p[4] = {f2h(v.x), f2h(v.y), f2h(v.z), f2h(v.w)};
  *(uint2*)&Wf[idx] = *(uint2*)p;
}

// ---------------- Kernel 1: projections, f16 32x32x16 MFMA ----------------
// grid (256, 12): 64 m-rows x combo(mat*4+h). K (scaled by log2e) -> linear f16;
// Q -> FRAG-MAJOR f16; V -> FRAG-MAJOR V^T bf16.
__global__ __launch_bounds__(256) void proj_kernel(
    const float* __restrict__ x, const unsigned short* __restrict__ Wf,
    const float* __restrict__ bk, const float* __restrict__ bq, const float* __restrict__ bv,
    unsigned short* __restrict__ Kf, unsigned short* __restrict__ Qf,
    unsigned short* __restrict__ Vtg) {
  __shared__ unsigned short xs[64 * AST];
  __shared__ unsigned short ob[64 * AST];
  const int t = threadIdx.x;
  const int r0 = blockIdx.x * 64;
  const int combo = blockIdx.y, mat = combo >> 2, h = combo & 3;
  const int n = r0 >> 10, ml = r0 & 1023;
  const float* bias = mat == 0 ? bk : (mat == 1 ? bq : bv);

#pragma unroll
  for (int rep = 0; rep < 2; ++rep) {
    int idx = rep * 256 + t, row = idx >> 3, c8 = (idx & 7) * 8;
    float4 a = *(const float4*)&x[(size_t)(r0 + row) * DD + c8];
    float4 b = *(const float4*)&x[(size_t)(r0 + row) * DD + c8 + 4];
    unsigned short p[8] = {f2h(a.x), f2h(a.y), f2h(a.z), f2h(a.w),
                           f2h(b.x), f2h(b.y), f2h(b.z), f2h(b.w)};
    *(uint4*)&xs[row * AST + c8] = *(uint4*)p;
  }
  __syncthreads();

  const int w = t >> 6, lane = t & 63, m31 = lane & 31, hf = lane >> 5;
  const int mi = w >> 1, ne = w & 1;
  const int ecol = h * 64 + ne * 32 + m31;
  const float bb = bias[ecol];

  f32x16 C;
#pragma unroll
  for (int r = 0; r < 16; ++r) C[r] = 0.f;
#pragma unroll
  for (int ks = 0; ks < 4; ++ks) {
    f16x8 xa = *(f16x8*)&xs[(mi * 32 + m31) * AST + ks * 16 + hf * 8];
    f16x8 wb = *(const f16x8*)&Wf[(size_t)mat * 16384 + (size_t)ecol * DD + ks * 16 + hf * 8];
    C = __builtin_amdgcn_mfma_f32_32x32x16_f16(xa, wb, C, 0, 0, 0);
  }

  if (mat < 2) {
    const float ksc = (mat == 0) ? LOG2E : 1.0f;  // fold exp's log2e into K
#pragma unroll
    for (int r = 0; r < 16; ++r) {
      int rr = (r & 3) + 8 * (r >> 2) + 4 * hf;
      ob[(mi * 32 + rr) * AST + ne * 32 + m31] = f2h((C[r] + bb) * ksc);
    }
  } else {
    // V transposed staging: ob[e][m_local], bf16
#pragma unroll
    for (int r = 0; r < 16; ++r) {
      int rr = (r & 3) + 8 * (r >> 2) + 4 * hf;
      ob[(ne * 32 + m31) * AST + mi * 32 + rr] = f2bf(C[r] + bb);
    }
  }
  __syncthreads();

  if (mat == 0) {
    // K: linear (n,h,m,e) — attn reads kfrag once per block
    const size_t obase = (((size_t)n * HH + h) * MM + ml) * DD;
#pragma unroll
    for (int rep = 0; rep < 2; ++rep) {
      int idx = rep * 256 + t, row = idx >> 3, c8 = (idx & 7) * 8;
      *(uint4*)&Kf[obase + (size_t)row * DD + c8] = *(uint4*)&ob[row * AST + c8];
    }
  } else if (mat == 1) {
    // Q frag-major: dst short-offset = base + ml*64 + idx*8, where
    // idx = jb32l*256 + ks*64 + hf2*32 + mr  <->  frag (jb32=ml/32+jb32l, ks, hf2, mr)
    const size_t obase = (((size_t)n * HH + h) * MM + ml) * DD;
#pragma unroll
    for (int rep = 0; rep < 2; ++rep) {
      int idx = rep * 256 + t;
      int jb32l = idx >> 8, ks = (idx >> 6) & 3, hf2 = (idx >> 5) & 1, mr = idx & 31;
      *(uint4*)&Qf[obase + (size_t)idx * 8] =
          *(uint4*)&ob[(jb32l * 32 + mr) * AST + ks * 16 + hf2 * 8];
    }
  } else {
    // V^T frag-major: dst short-offset = baseT + (ml/64)*4096 + idx*8, where
    // idx = ks*128 + eh*64 + hf2*32 + mr  <->  frag (jt=ml/64, ks, eh, hf2, mr)
    const size_t obaseT = (((size_t)n * HH + h) * DD) * MM + (size_t)(ml >> 6) * 4096;
#pragma unroll
    for (int rep = 0; rep < 2; ++rep) {
      int idx = rep * 256 + t;
      int ks = idx >> 7, eh = (idx >> 6) & 1, hf2 = (idx >> 5) & 1, mr = idx & 31;
      *(uint4*)&Vtg[obaseT + (size_t)idx * 8] =
          *(uint4*)&ob[(eh * 32 + mr) * AST + ks * 16 + hf2 * 8];
    }
  }
}

// ---------------- Kernel 2: flash attention, LDS-free + reg double-buffer ----------------
// grid (8, H, N), 256 thr = 4 waves, decoupled. Per j-tile: 16 coalesced frag loads
// (issued one full tile ahead into the other named buffer set) + 16 MFMA + in-reg softmax.
// Zero LDS / zero barriers in loop; single barrier at epilogue for coalesced DX store.

#define LOADF(qa0_, qa1_, bv0_, bv1_, jtn)                         \
  do {                                                             \
    const unsigned short* Qj_ = Qp + (size_t)(jtn) * 4096;         \
    const unsigned short* Vj_ = Vp + (size_t)(jtn) * 4096;         \
    _Pragma("unroll") for (int ks = 0; ks < 4; ++ks) {             \
      qa0_[ks] = *(const f16x8*)&Qj_[ks * 512 + loff];             \
      qa1_[ks] = *(const f16x8*)&Qj_[2048 + ks * 512 + loff];      \
      bv0_[ks] = *(const bf16x8*)&Vj_[ks * 1024 + loff];           \
      bv1_[ks] = *(const bf16x8*)&Vj_[ks * 1024 + 512 + loff];     \
    }                                                              \
  } while (0)

#define SOFTPACK(C_, dst0_, dst1_)                                             \
  do {                                                                         \
    _Pragma("unroll") for (int r = 0; r < 16; ++r) {                           \
      float s = C_[r];                                                         \
      s = fmaxf(s, NEG * s);                                                   \
      s = __builtin_amdgcn_exp2f(s);                                           \
      lac += s;                                                                \
      C_[r] = s;                                                               \
    }                                                                          \
    {                                                                          \
      unsigned int p01 = pk_bf16(C_[0], C_[1]), p23 = pk_bf16(C_[2], C_[3]);   \
      unsigned int p45 = pk_bf16(C_[4], C_[5]), p67 = pk_bf16(C_[6], C_[7]);   \
      swap32(p01, p45);                                                        \
      swap32(p23, p67);                                                        \
      uint4v wlo = {p01, p23, p45, p67};                                       \
      dst0_ = __builtin_bit_cast(bf16x8, wlo);                                 \
      unsigned int p89 = pk_bf16(C_[8], C_[9]), pAB = pk_bf16(C_[10], C_[11]); \
      unsigned int pCD = pk_bf16(C_[12], C_[13]), pEF = pk_bf16(C_[14], C_[15]); \
      swap32(p89, pCD);                                                        \
      swap32(pAB, pEF);                                                        \
      uint4v whi = {p89, pAB, pCD, pEF};                                       \
      dst1_ = __builtin_bit_cast(bf16x8, whi);                                 \
    }                                                                          \
  } while (0)

#define COMPUTE(qa0_, qa1_, bv0_, bv1_)                                         \
  do {                                                                          \
    bf16x8 pa[4];                                                               \
    f32x16 C;                                                                   \
    _Pragma("unroll") for (int r = 0; r < 16; ++r) C[r] = 0.f;                  \
    _Pragma("unroll") for (int ks = 0; ks < 4; ++ks)                            \
        C = __builtin_amdgcn_mfma_f32_32x32x16_f16(qa0_[ks], kfrag[ks], C, 0, 0, 0); \
    SOFTPACK(C, pa[0], pa[1]);                                                  \
    _Pragma("unroll") for (int r = 0; r < 16; ++r) C[r] = 0.f;                  \
    _Pragma("unroll") for (int ks = 0; ks < 4; ++ks)                            \
        C = __builtin_amdgcn_mfma_f32_32x32x16_f16(qa1_[ks], kfrag[ks], C, 0, 0, 0); \
    SOFTPACK(C, pa[2], pa[3]);                                                  \
    _Pragma("unroll") for (int ks = 0; ks < 4; ++ks) {                          \
      agg0 = __builtin_amdgcn_mfma_f32_32x32x16_bf16(pa[ks], bv0_[ks], agg0, 0, 0, 0); \
      agg1 = __builtin_amdgcn_mfma_f32_32x32x16_bf16(pa[ks], bv1_[ks], agg1, 0, 0, 0); \
    }                                                                           \
  } while (0)

__global__ __launch_bounds__(256, 2) void attn_kernel(
    const unsigned short* __restrict__ Kf, const unsigned short* __restrict__ Qf,
    const unsigned short* __restrict__ Vtg, const float* __restrict__ x,
    unsigned short* __restrict__ DX) {
  __shared__ __align__(16) unsigned short sm[128 * AST];  // epilogue dx staging only

  const int t = threadIdx.x;
  const int w = t >> 6, lane = t & 63;
  const int m31 = lane & 31, hf = lane >> 5;

  // XCD-bijective swizzle: xcd = slot&7 gets 8 whole (n,h) groups.
  const int slot = blockIdx.x + 8 * (blockIdx.y + HH * (int)blockIdx.z);  // 0..511
  const int xcd = slot & 7, within = slot >> 3;
  const int grp = xcd * 8 + (within >> 3);  // 0..63 = n*4+h
  const int ib = within & 7;
  const int n = grp >> 2, h = grp & 3;
  const int i0 = ib * 128;

  const size_t base = (((size_t)n * HH + h) * MM) * DD;
  const size_t baseT = (((size_t)n * HH + h) * DD) * MM;
  const unsigned short* Qp = Qf + base;
  const unsigned short* Vp = Vtg + baseT;

  // K fragments: B-operand cols i = i0 + w*32 + m31 (log2e pre-folded in proj)
  f16x8 kfrag[4];
#pragma unroll
  for (int ks = 0; ks < 4; ++ks)
    kfrag[ks] = *(const f16x8*)&Kf[base + (size_t)(i0 + w * 32 + m31) * DD + ks * 16 + hf * 8];

  f32x16 agg0, agg1;
#pragma unroll
  for (int r = 0; r < 16; ++r) { agg0[r] = 0.f; agg1[r] = 0.f; }
  float lac = 0.f;

  const int loff = hf * 256 + m31 * 8;  // lane term, shared by all frag loads

  // named double-buffer sets (all indices literal — rule #20)
  f16x8 Aq0[4], Aq1[4], Bq0[4], Bq1[4];
  bf16x8 Av0[4], Av1[4], Bv0[4], Bv1[4];

  LOADF(Aq0, Aq1, Av0, Av1, 0);
  for (int g = 0; g < 8; ++g) {
    LOADF(Bq0, Bq1, Bv0, Bv1, 2 * g + 1);   // prefetch odd tile
    COMPUTE(Aq0, Aq1, Av0, Av1);            // compute even tile (loaded last iter)
    if (g < 7) LOADF(Aq0, Aq1, Av0, Av1, 2 * g + 2);  // prefetch next even tile
    COMPUTE(Bq0, Bq1, Bv0, Bv1);            // compute odd tile
  }

  // denom: lsum(lane) = l[row m31] (both halves); broadcast to row rr via shfl.
  const float lsum = lac + __shfl_xor(lac, 32);

  // epilogue: dx = leaky(agg/l) - x -> f16 stage in sm -> coalesced store (concat layout)
#pragma unroll
  for (int r = 0; r < 16; ++r) {
    const int rr = (r & 3) + 8 * (r >> 2) + 4 * hf;
    const float rl = 1.0f / __shfl(lsum, rr);
    const size_t xrow = ((size_t)n * MM + i0 + w * 32 + rr) * DD;
    float v0 = agg0[r] * rl;
    v0 = fmaxf(v0, NEG * v0);
    v0 -= x[xrow + m31];
    sm[(w * 32 + rr) * AST + m31] = f2h(v0);
    float v1 = agg1[r] * rl;
    v1 = fmaxf(v1, NEG * v1);
    v1 -= x[xrow + 32 + m31];
    sm[(w * 32 + rr) * AST + 32 + m31] = f2h(v1);
  }
  __syncthreads();
#pragma unroll
  for (int rep = 0; rep < 4; ++rep) {
    const int idx = rep * 256 + t, row = idx >> 3, cc = (idx & 7) * 8;
    *(uint4*)&DX[((size_t)n * MM + i0 + row) * (HH * DD) + h * DD + cc] =
        *(uint4*)&sm[row * AST + cc];
  }
}

// ---------------- Kernel 3: decoder, f16 32x32x16 MFMA ----------------
__global__ __launch_bounds__(256) void dec_kernel(
    const unsigned short* __restrict__ DX, const unsigned short* __restrict__ Wdf,
    const float* __restrict__ bdec, float* __restrict__ out) {
  __shared__ unsigned short dxs[64 * DST];
  const int t = threadIdx.x;
  const int w = t >> 6, lane = t & 63, m31 = lane & 31, hf = lane >> 5;
  const int mi = w >> 1, nd = w & 1;
  const int r0 = blockIdx.x * 64;
#pragma unroll
  for (int rep = 0; rep < 8; ++rep) {
    int idx = rep * 256 + t, row = idx >> 5, c8 = (idx & 31) * 8;
    *(uint4*)&dxs[row * DST + c8] = *(const uint4*)&DX[(size_t)(r0 + row) * 256 + c8];
  }
  __syncthreads();
  const float bb = bdec[nd * 32 + m31];
  f32x16 C;
#pragma unroll
  for (int r = 0; r < 16; ++r) C[r] = 0.f;
#pragma unroll
  for (int ks = 0; ks < 16; ++ks) {
    f16x8 aD = *(f16x8*)&dxs[(mi * 32 + m31) * DST + ks * 16 + hf * 8];
    f16x8 bW = *(const f16x8*)&Wdf[(size_t)(nd * 32 + m31) * 256 + ks * 16 + hf * 8];
    C = __builtin_amdgcn_mfma_f32_32x32x16_f16(aD, bW, C, 0, 0, 0);
  }
#pragma unroll
  for (int r = 0; r < 16; ++r) {
    int rr = (r & 3) + 8 * (r >> 2) + 4 * hf;
    out[(size_t)(r0 + mi * 32 + rr) * DD + nd * 32 + m31] = C[r] + bb;
  }
}

extern "C" void kernel_launch(void* const* d_in, const int* in_sizes, int n_in,
                              void* d_out, int out_size, void* d_ws, size_t ws_size,
                              hipStream_t stream) {
  const float* x    = (const float*)d_in[0];
  const float* Wk   = (const float*)d_in[2];
  const float* bk   = (const float*)d_in[3];
  const float* Wq   = (const float*)d_in[4];
  const float* bq   = (const float*)d_in[5];
  const float* Wv   = (const float*)d_in[6];
  const float* bv   = (const float*)d_in[7];
  const float* Wdec = (const float*)d_in[8];
  const float* bdec = (const float*)d_in[9];
  float* out = (float*)d_out;

  const size_t seg = (size_t)NB * HH * MM * DD;
  unsigned short* Kf  = (unsigned short*)d_ws;
  unsigned short* Qf  = Kf + seg;
  unsigned short* Vt  = Qf + seg;
  unsigned short* DXp = Vt + seg;
  unsigned short* Wf  = DXp + seg;
  unsigned short* Wdf = Wf + 3 * 16384;

  prep_kernel<<<64, 256, 0, stream>>>(Wk, Wq, Wv, Wdec, Wf);
  proj_kernel<<<dim3(256, 12), 256, 0, stream>>>(x, Wf, bk, bq, bv, Kf, Qf, Vt);
  attn_kernel<<<dim3(8, HH, NB), 256, 0, stream>>>(Kf, Qf, Vt, x, DXp);
  dec_kernel<<<NB * MM / 64, 256, 0, stream>>>(DXp, Wdf, bdec, out);
}